// Round 12
// baseline (544.643 us; speedup 1.0000x reference)
//
#include <hip/hip_runtime.h>

// STKBranch double-softmax attention, R22: two-kernel pass-split.
//   Ledger: R17 single-kernel 99.5us (bench 166.1, best); R20 = 89.5 main +
//   15 prep = 104.5; R18/R21 proved f32 K staging spills at the 1024-thr
//   64-VGPR cap. Fix: split by PASS so each kernel gets the register frame
//   and occupancy it needs, and prep rides along with pass 1:
//   - Kernel A (512thr, (512,8), 18.4KB LDS -> 32 waves/CU):
//       grid 1536 = 512 V-transpose-prep blocks (R20's LDS-transpose code)
//       + 1024 key-split pass-1 blocks (bh,qt,g): s1 partials over 1024 keys,
//       K staged f32->f16 in-kernel (fits: no O/V/pfr state). qt==0 blocks
//       side-write their converted f16 K tiles to wsK (no separate K-prep
//       read; +16.8MB writes).
//   - Kernel B (1024thr key-split, (1024,8), 73.7KB LDS): R20's pass 2
//     verbatim (proven spill-free); s1 loaded from ws partials (2 adds).
//   All compute paths identical to R17/R20: swapped QK^T (C=KxQ^T), P in
//   regs as PV B-frag, permuted Vt cols -> b128 PV reads, pair interleave,
//   ones-MFMA l2, setprio, QS=72 bank-floor LDS.
// Math: L = scale*q@k^T ; w = softmax(2L) ; attn = softmax(L*w) ; out = attn@v
// |L| <= ~7 -> no max-subtraction. B=4 H=8 N=2048 D=64 fp32 io.

typedef _Float16 f16;
typedef f16 f16x8 __attribute__((ext_vector_type(8)));
typedef f16 f16x4 __attribute__((ext_vector_type(4)));
typedef float f32x4 __attribute__((ext_vector_type(4)));

#define MFMA32(a, b, c) __builtin_amdgcn_mfma_f32_16x16x32_f16((a), (b), (c), 0, 0, 0)
#define MFMA16(a, b, c) __builtin_amdgcn_mfma_f32_16x16x16f16((a), (b), (c), 0, 0, 0)
#define EXP2(x) __builtin_amdgcn_exp2f(x)   // v_exp_f32: D = 2^S0

#define N_CTX 2048
#define DH 64
#define KT 64
#define NKT_G 16          // tiles per key-group (1024 keys / KT)
#define QS 72             // LDS row stride (f16): 144 B (bank-floor, proven)
#define KSB (KT * QS)     // 4608 f16 = one Ks/Vt buffer (9216 B)
#define SMEM_A 18432      // A: pass1 Ks dbuf == Vprep 2 tiles (both 18432 B)
#define SMEM_B (4 * 2 * KSB * 2)   // 73728 B
#define WS_HALF ((size_t)32 * N_CTX * DH)   // 4,194,304 f16 per ws tensor

#define C2 2.885390081777927f    // 2*log2(e), folded into Q fragments

__device__ inline unsigned pk(float a, float b) {
    typedef __fp16 fp16x2_t __attribute__((ext_vector_type(2)));
    union { fp16x2_t v; unsigned u; } x;
    x.v = __builtin_amdgcn_cvt_pkrtz(a, b);
    return x.u;
}

// ================= Kernel A: V-prep + pass 1 (+ K side-write) =================
// wsV[bh*131072 + t*4096 + d*64 + c], c(key)=((key>>2)&3)*16+((key>>4)&3)*4+(key&3)
// wsK[bh*131072 + key*64 + d]
// wsS[g*65536 + bh*2048 + row] = s1 partial over keys [g*1024,(g+1)*1024)
__global__ __launch_bounds__(512, 8)
void stk_p1(const float* __restrict__ qg, const float* __restrict__ kg,
            const float* __restrict__ vg, const float* __restrict__ sg,
            f16* __restrict__ wsK, f16* __restrict__ wsV,
            float* __restrict__ wsS) {
    extern __shared__ f16 smem[];
    const int bid = blockIdx.x, tid = threadIdx.x;

    if (bid < 512) {
        // ---- V transpose prep: head bh, tiles 2j + (tid>>8) ----
        const int bh = bid >> 4, t = ((bid & 15) << 1) | (tid >> 8);
        const int t2 = tid & 255;
        f16* lds = smem + (tid >> 8) * (DH * QS);
        const int p = t2 >> 3, dseg = t2 & 7, d0 = dseg * 8;
        const int c0 = ((p >> 1) & 3) * 16 + ((p >> 3) & 3) * 4 + (p & 1) * 2;
        const float* base = vg + (((size_t)(bh * 2048 + t * 64 + 2 * p)) << 6) + d0;
        float4 a0 = *(const float4*)(base);
        float4 a1 = *(const float4*)(base + 4);
        float4 b0 = *(const float4*)(base + 64);
        float4 b1 = *(const float4*)(base + 68);
        #pragma unroll
        for (int j = 0; j < 4; ++j) {
            *(unsigned*)&lds[(d0 + j) * QS + c0] =
                pk(((const float*)&a0)[j], ((const float*)&b0)[j]);
            *(unsigned*)&lds[(d0 + 4 + j) * QS + c0] =
                pk(((const float*)&a1)[j], ((const float*)&b1)[j]);
        }
        __syncthreads();
        const int d = t2 >> 2, cs = t2 & 3;
        f16x8 r0 = *(const f16x8*)&lds[d * QS + cs * 16];
        f16x8 r1 = *(const f16x8*)&lds[d * QS + cs * 16 + 8];
        f16* dst = wsV + ((((size_t)bh * 32 + t) << 6) + d) * 64 + cs * 16;
        *(f16x8*)(dst) = r0;
        *(f16x8*)(dst + 8) = r1;
        return;
    }

    // ---- pass 1: block (bh, qt, g); s1 partial over this group's 1024 keys ----
    const int idx = bid - 512;
    const int bh = idx & 31, qt = (idx >> 5) & 15, g = idx >> 9;
    const int wv = tid >> 6, lane = tid & 63, l15 = lane & 15, q4 = lane >> 4;
    const int q0 = qt * 128;
    const float scale2 = sg[0] * C2;
    const float* qb  = qg + (size_t)bh * N_CTX * DH;
    const float* kbg = kg + ((size_t)bh * N_CTX + g * (NKT_G * KT)) * DH;
    f16* const wsKg  = wsK + ((size_t)bh << 17) + (size_t)g * (NKT_G * KT) * DH;
    const bool sw = (qt == 0);   // side-write converted K tiles to wsK

    // Q fragments (B operand of swapped QK^T)
    f16x8 aq[2];
    {
        const float* qrow = qb + (size_t)(q0 + wv * 16 + l15) * DH;
        #pragma unroll
        for (int kc = 0; kc < 2; ++kc) {
            float4 a0 = *(const float4*)&qrow[kc * 32 + q4 * 8];
            float4 a1 = *(const float4*)&qrow[kc * 32 + q4 * 8 + 4];
            union { f16x8 h; unsigned u[4]; } A;
            A.u[0] = pk(a0.x * scale2, a0.y * scale2);
            A.u[1] = pk(a0.z * scale2, a0.w * scale2);
            A.u[2] = pk(a1.x * scale2, a1.y * scale2);
            A.u[3] = pk(a1.z * scale2, a1.w * scale2);
            aq[kc] = A.h;
        }
    }

    int kofs[2], gofs[2];
    #pragma unroll
    for (int it = 0; it < 2; ++it) {
        int i2 = it * 512 + tid;
        gofs[it] = (i2 >> 4) * DH + (i2 & 15) * 4;   // f32 offset in tile (also wsK f16 offset)
        kofs[it] = (i2 >> 4) * QS + (i2 & 15) * 4;   // LDS f16 offset
    }
    f16* const ksBase = smem;
    const f16* const ks_r = ksBase + l15 * QS + q4 * 8;

    float s1 = 0.f;
    float4 kr[2];
    #pragma unroll
    for (int it = 0; it < 2; ++it)
        kr[it] = *(const float4*)&kbg[gofs[it]];
    #pragma unroll
    for (int it = 0; it < 2; ++it) {
        uint2 c = make_uint2(pk(kr[it].x, kr[it].y), pk(kr[it].z, kr[it].w));
        *(uint2*)&ksBase[kofs[it]] = c;
        if (sw) *(uint2*)&wsKg[gofs[it]] = c;        // tile 0
    }
    #pragma unroll
    for (int it = 0; it < 2; ++it)
        kr[it] = *(const float4*)&kbg[KT * DH + gofs[it]];
    __syncthreads();

    for (int kt = 0; kt < NKT_G; ++kt) {
        const int cur = (kt & 1) * KSB, nxt = KSB - cur;
        const int tw = (kt + 1 < NKT_G) ? kt + 1 : NKT_G - 1;  // tile in regs
        #pragma unroll
        for (int it = 0; it < 2; ++it) {
            uint2 c = make_uint2(pk(kr[it].x, kr[it].y), pk(kr[it].z, kr[it].w));
            *(uint2*)&ksBase[nxt + kofs[it]] = c;
            if (sw) *(uint2*)&wsKg[(size_t)tw * (KT * DH) + gofs[it]] = c;
        }
        {
            int tn = (kt + 2 < NKT_G) ? kt + 2 : NKT_G - 1;
            #pragma unroll
            for (int it = 0; it < 2; ++it)
                kr[it] = *(const float4*)&kbg[(size_t)tn * KT * DH + gofs[it]];
        }
        __builtin_amdgcn_s_setprio(1);
        #pragma unroll
        for (int kgi = 0; kgi < 4; ++kgi) {
            f16x8 b0 = *(const f16x8*)&ks_r[cur + kgi * 16 * QS];
            f16x8 b1 = *(const f16x8*)&ks_r[cur + kgi * 16 * QS + 32];
            f32x4 acc = {0.f, 0.f, 0.f, 0.f};
            acc = MFMA32(b0, aq[0], acc);   // swapped: C[key][q], lane q = l15
            acc = MFMA32(b1, aq[1], acc);
            s1 += (EXP2(acc[0]) + EXP2(acc[1])) + (EXP2(acc[2]) + EXP2(acc[3]));
        }
        __builtin_amdgcn_s_setprio(0);
        __syncthreads();
    }
    s1 += __shfl_xor(s1, 16, 64);
    s1 += __shfl_xor(s1, 32, 64);
    if (lane < 16)
        wsS[(size_t)g * 65536 + (size_t)bh * 2048 + q0 + wv * 16 + lane] = s1;
}

// ================= Kernel B: pass 2 (key-split 1024-thr, R20-proven) =================
__global__ __launch_bounds__(1024, 8)
void stk_p2(const float* __restrict__ qg, const f16* __restrict__ wsK,
            const f16* __restrict__ wsV, const float* __restrict__ wsS,
            const float* __restrict__ sg, float* __restrict__ og) {
    extern __shared__ f16 smem[];

    const int tid  = threadIdx.x;
    const int wv   = tid >> 6;        // 0..15
    const int grp  = wv >> 3;         // key-group 0/1
    const int wv7  = wv & 7;
    const int lane = tid & 63;
    const int l15  = lane & 15;
    const int q4   = lane >> 4;
    const int tg   = (wv7 << 6) | lane;  // tid within group, 0..511
    const int bh   = blockIdx.x & 31; // XCD swizzle
    const int q0   = (blockIdx.x >> 5) * 128;
    const float scale2 = sg[0] * C2;

    const float* qb = qg + (size_t)bh * N_CTX * DH;
    float*       ob = og + (size_t)bh * N_CTX * DH;
    const f16* wsKh = wsK + ((size_t)bh << 17);
    const f16* wsVh = wsV + ((size_t)bh << 17);
    const int T0 = grp * NKT_G;

    f16x8 aq[2];
    {
        const float* qrow = qb + (size_t)(q0 + wv7 * 16 + l15) * DH;
        #pragma unroll
        for (int kc = 0; kc < 2; ++kc) {
            float4 a0 = *(const float4*)&qrow[kc * 32 + q4 * 8];
            float4 a1 = *(const float4*)&qrow[kc * 32 + q4 * 8 + 4];
            union { f16x8 h; unsigned u[4]; } A;
            A.u[0] = pk(a0.x * scale2, a0.y * scale2);
            A.u[1] = pk(a0.z * scale2, a0.w * scale2);
            A.u[2] = pk(a1.x * scale2, a1.y * scale2);
            A.u[3] = pk(a1.z * scale2, a1.w * scale2);
            aq[kc] = A.h;
        }
    }

    f16* const ksBase = smem + grp * (2 * KSB);
    f16* const vtBase = smem + 2 * (2 * KSB) + grp * (2 * KSB);
    float* const obuf = (float*)smem;   // epilogue reuse

    const int sofs = tg * 8;
    const int wofs = (tg >> 3) * QS + (tg & 7) * 8;
    const f16* const ks_r = ksBase + l15 * QS + q4 * 8;
    const f16* const vt_r = vtBase + l15 * QS + q4 * 16;

    // merged s1 from pass-1 partials (all lanes with same l15 broadcast-read)
    const size_t srow = (size_t)bh * 2048 + q0 + wv7 * 16 + l15;
    const float s1 = wsS[srow] + wsS[65536 + srow];
    const float inv1 = 0.5f / s1;    // e2 = exp2((acc*e1) * 0.5/s1)

    f32x4 O[4];
    #pragma unroll
    for (int dt = 0; dt < 4; ++dt) O[dt] = (f32x4){0.f, 0.f, 0.f, 0.f};
    f32x4 Oe = {0.f, 0.f, 0.f, 0.f};
    const f16x4 ones = {(f16)1.f, (f16)1.f, (f16)1.f, (f16)1.f};

    f16* const ks_w = ksBase;
    f16* const vt_w = vtBase;
    f16x8 krh, vrh;
    krh = *(const f16x8*)&wsKh[(size_t)T0 * 4096 + sofs];
    vrh = *(const f16x8*)&wsVh[(size_t)T0 * 4096 + sofs];
    *(f16x8*)&ks_w[wofs] = krh;
    *(f16x8*)&vt_w[wofs] = vrh;
    krh = *(const f16x8*)&wsKh[(size_t)(T0 + 1) * 4096 + sofs];
    vrh = *(const f16x8*)&wsVh[(size_t)(T0 + 1) * 4096 + sofs];
    __syncthreads();

    for (int kt = 0; kt < NKT_G; ++kt) {
        const int cur = (kt & 1) * KSB, nxt = KSB - cur;
        *(f16x8*)&ks_w[nxt + wofs] = krh;
        *(f16x8*)&vt_w[nxt + wofs] = vrh;
        { int tn = (kt + 2 < NKT_G) ? kt + 2 : NKT_G - 1;
          krh = *(const f16x8*)&wsKh[(size_t)(T0 + tn) * 4096 + sofs];
          vrh = *(const f16x8*)&wsVh[(size_t)(T0 + tn) * 4096 + sofs]; }
        __builtin_amdgcn_s_setprio(1);
        #pragma unroll
        for (int p = 0; p < 2; ++p) {
            f16x4 pfr[2];
            #pragma unroll
            for (int h = 0; h < 2; ++h) {
                const int kgi = p * 2 + h;
                f16x8 b0 = *(const f16x8*)&ks_r[cur + kgi * 16 * QS];
                f16x8 b1 = *(const f16x8*)&ks_r[cur + kgi * 16 * QS + 32];
                f32x4 acc = {0.f, 0.f, 0.f, 0.f};
                acc = MFMA32(b0, aq[0], acc);
                acc = MFMA32(b1, aq[1], acc);
                float e2r[4];
                #pragma unroll
                for (int r = 0; r < 4; ++r) {
                    float a  = acc[r];
                    float e1 = EXP2(a);
                    e2r[r] = EXP2((a * e1) * inv1);
                }
                union { f16x4 hh; unsigned u[2]; } P;
                P.u[0] = pk(e2r[0], e2r[1]);
                P.u[1] = pk(e2r[2], e2r[3]);
                pfr[h] = P.hh;
                Oe = MFMA16(ones, pfr[h], Oe);
            }
            #pragma unroll
            for (int dt = 0; dt < 4; ++dt) {
                f16x8 av = *(const f16x8*)&vt_r[cur + dt * 16 * QS + p * 8];
                f16x4 alo = __builtin_shufflevector(av, av, 0, 1, 2, 3);
                f16x4 ahi = __builtin_shufflevector(av, av, 4, 5, 6, 7);
                O[dt] = MFMA16(alo, pfr[0], O[dt]);
                O[dt] = MFMA16(ahi, pfr[1], O[dt]);
            }
        }
        __builtin_amdgcn_s_setprio(0);
        __syncthreads();
    }

    // cross-group merge via dead Ks/Vt LDS; group 0 writes
    const int rec = tg * 20;
    if (grp) {
        #pragma unroll
        for (int dt = 0; dt < 4; ++dt)
            *(f32x4*)&obuf[rec + dt * 4] = O[dt];
        obuf[rec + 16] = Oe[0];
    }
    __syncthreads();
    if (!grp) {
        #pragma unroll
        for (int dt = 0; dt < 4; ++dt)
            O[dt] += *(const f32x4*)&obuf[rec + dt * 4];
        const float invl2 = 1.0f / (Oe[0] + obuf[rec + 16]);
        const size_t orow = (size_t)(q0 + wv7 * 16 + l15) * DH;
        #pragma unroll
        for (int dt = 0; dt < 4; ++dt) {
            float4 o;
            o.x = O[dt][0] * invl2;
            o.y = O[dt][1] * invl2;
            o.z = O[dt][2] * invl2;
            o.w = O[dt][3] * invl2;
            *(float4*)&ob[orow + dt * 16 + q4 * 4] = o;
        }
    }
}

extern "C" void kernel_launch(void* const* d_in, const int* in_sizes, int n_in,
                              void* d_out, int out_size, void* d_ws, size_t ws_size,
                              hipStream_t stream) {
    const float* q = (const float*)d_in[0];
    const float* k = (const float*)d_in[1];
    const float* v = (const float*)d_in[2];
    const float* s = (const float*)d_in[3];
    float* out = (float*)d_out;
    f16* wsK = (f16*)d_ws;                    // 8 MB
    f16* wsV = wsK + WS_HALF;                 // 8 MB
    float* wsS = (float*)(wsV + WS_HALF);     // 512 KB (2 x 32 x 2048 f32)
    stk_p1<<<dim3(1536), dim3(512), SMEM_A, stream>>>(q, k, v, s, wsK, wsV, wsS);
    stk_p2<<<dim3(512), dim3(1024), SMEM_B, stream>>>(q, wsK, wsV, wsS, s, out);
}

// Round 13
// 224.115 us; speedup vs baseline: 2.4302x; 2.4302x over previous
//
#include <hip/hip_runtime.h>

// STKBranch double-softmax attention, R23: fat waves at 16 waves/CU.
//   Floor arithmetic per CU: LDS reads ~40us >> VALU ~28 >> MFMA ~25. LDS
//   scales with wave count (each wave reads the full K/V tile). R13's fat
//   waves halved LDS but died at 8 waves/CU. Retry inside the key-split
//   structure at 16 waves/CU with the 128-VGPR cap:
//   - 1024-thr blocks, __launch_bounds__(1024,4) -> 1 block/CU, cap 128
//     (R18/R21/R22 all spilled at the 64 cap; this removes the cliff).
//   - 2 key-groups x 8 waves x 32 q-rows/wave = 256 rows/block, grid 256
//     (32 bh x 8 qt). Per-unit-work LDS reads HALVE vs R17/R20.
//   - K staged f32->f16 in-kernel (R17 path, fits at cap 128); V from the
//     proven V-only transpose prep (~8us, 50MB). l2 on VALU (ones-MFMA was
//     neutral; saves 6 regs). Cross-group merge: s1 via sred, O/l2 via the
//     dead Ks/Vt LDS (512 x 144B records = exactly 73728B).
//   - compute paths unchanged: swapped QK^T (C=KxQ^T), P in regs as PV
//     B-frag, permuted Vt cols -> b128 PV reads (A-frags shared across qc),
//     pair interleave, setprio, QS=72 bank-floor LDS.
// Math: L = scale*q@k^T ; w = softmax(2L) ; attn = softmax(L*w) ; out = attn@v
// |L| <= ~7 -> no max-subtraction. B=4 H=8 N=2048 D=64 fp32 io.

typedef _Float16 f16;
typedef f16 f16x8 __attribute__((ext_vector_type(8)));
typedef f16 f16x4 __attribute__((ext_vector_type(4)));
typedef float f32x4 __attribute__((ext_vector_type(4)));

#define MFMA32(a, b, c) __builtin_amdgcn_mfma_f32_16x16x32_f16((a), (b), (c), 0, 0, 0)
#define MFMA16(a, b, c) __builtin_amdgcn_mfma_f32_16x16x16f16((a), (b), (c), 0, 0, 0)
#define EXP2(x) __builtin_amdgcn_exp2f(x)   // v_exp_f32: D = 2^S0

#define N_CTX 2048
#define DH 64
#define KT 64
#define NKT_G 16          // tiles per key-group (1024 keys / KT)
#define QS 72             // LDS row stride (f16): 144 B (bank-floor, proven)
#define KSB (KT * QS)     // 4608 f16 = one Ks/Vt buffer (9216 B)
#define SMEM_BYTES (4 * 2 * KSB * 2 + 2048)   // 73728 + 2048(sred) = 75776 B

#define C2 2.885390081777927f    // 2*log2(e), folded into Q fragments

__device__ inline unsigned pk(float a, float b) {
    typedef __fp16 fp16x2_t __attribute__((ext_vector_type(2)));
    union { fp16x2_t v; unsigned u; } x;
    x.v = __builtin_amdgcn_cvt_pkrtz(a, b);
    return x.u;
}

// ---------------- pre-pass: V -> f16 transposed workspace (R21-proven) --------
// wsV[bh*131072 + t*4096 + d*64 + c], c(key)=((key>>2)&3)*16+((key>>4)&3)*4+(key&3)
__global__ __launch_bounds__(256)
void stk_prep(const float* __restrict__ vg, f16* __restrict__ wsV) {
    __shared__ f16 lds[DH * QS];          // [d][c], stride 72
    const int tid = threadIdx.x;
    const int bh = blockIdx.x >> 5, t = blockIdx.x & 31;
    const int p = tid >> 3, dseg = tid & 7, d0 = dseg * 8;
    const int c0 = ((p >> 1) & 3) * 16 + ((p >> 3) & 3) * 4 + (p & 1) * 2;
    const float* base = vg + (((size_t)(bh * 2048 + t * 64 + 2 * p)) << 6) + d0;
    float4 a0 = *(const float4*)(base);
    float4 a1 = *(const float4*)(base + 4);
    float4 b0 = *(const float4*)(base + 64);
    float4 b1 = *(const float4*)(base + 68);
    #pragma unroll
    for (int j = 0; j < 4; ++j) {
        *(unsigned*)&lds[(d0 + j) * QS + c0] =
            pk(((const float*)&a0)[j], ((const float*)&b0)[j]);
        *(unsigned*)&lds[(d0 + 4 + j) * QS + c0] =
            pk(((const float*)&a1)[j], ((const float*)&b1)[j]);
    }
    __syncthreads();
    const int d = tid >> 2, cs = tid & 3;
    f16x8 r0 = *(const f16x8*)&lds[d * QS + cs * 16];
    f16x8 r1 = *(const f16x8*)&lds[d * QS + cs * 16 + 8];
    f16* dst = wsV + ((((size_t)bh * 32 + t) << 6) + d) * 64 + cs * 16;
    *(f16x8*)(dst) = r0;
    *(f16x8*)(dst + 8) = r1;
}

// ---------------- main kernel: fat-wave key-split ----------------
__global__ __launch_bounds__(1024, 4)
void stk_attn_mfma(const float* __restrict__ qg, const float* __restrict__ kg,
                   const f16* __restrict__ wsV, const float* __restrict__ sg,
                   float* __restrict__ og) {
    extern __shared__ f16 smem[];

    const int tid  = threadIdx.x;
    const int wv   = tid >> 6;        // 0..15
    const int grp  = wv >> 3;         // key-group 0/1
    const int wv7  = wv & 7;          // wave within group
    const int lane = tid & 63;
    const int l15  = lane & 15;
    const int q4   = lane >> 4;
    const int tg   = (wv7 << 6) | lane;  // tid within group, 0..511
    const int bh   = blockIdx.x & 31; // XCD swizzle: head h spread across XCDs
    const int q0   = (blockIdx.x >> 5) * 256;   // 8 q-tiles of 256 rows
    const float scale2 = sg[0] * C2;  // fold 2*log2e: acc = 2L*log2e

    const float* qb  = qg + (size_t)bh * N_CTX * DH;
    float*       ob  = og + (size_t)bh * N_CTX * DH;
    const float* kbg = kg + ((size_t)bh * N_CTX + grp * (NKT_G * KT)) * DH;
    const f16* wsVh  = wsV + ((size_t)bh << 17);
    const int T0 = grp * NKT_G;

    // ---- Q fragments: 2 q-subtiles per wave, rows q0 + wv7*32 + qc*16 + l15 ----
    f16x8 aq[2][2];
    #pragma unroll
    for (int qc = 0; qc < 2; ++qc) {
        const float* qrow = qb + (size_t)(q0 + wv7 * 32 + qc * 16 + l15) * DH;
        #pragma unroll
        for (int kc = 0; kc < 2; ++kc) {
            float4 a0 = *(const float4*)&qrow[kc * 32 + q4 * 8];
            float4 a1 = *(const float4*)&qrow[kc * 32 + q4 * 8 + 4];
            union { f16x8 h; unsigned u[4]; } A;
            A.u[0] = pk(a0.x * scale2, a0.y * scale2);
            A.u[1] = pk(a0.z * scale2, a0.w * scale2);
            A.u[2] = pk(a1.x * scale2, a1.y * scale2);
            A.u[3] = pk(a1.z * scale2, a1.w * scale2);
            aq[qc][kc] = A.h;
        }
    }

    // group-private LDS bases
    f16* const ksBase = smem + grp * (2 * KSB);
    f16* const vtBase = smem + 2 * (2 * KSB) + grp * (2 * KSB);
    float* const sred = (float*)(smem + 4 * (2 * KSB));   // 512 floats
    float* const obuf = (float*)smem;                     // epilogue reuse

    // staging offsets: idx = it*512 + tg
    int kofs[2], gofs[2];
    #pragma unroll
    for (int it = 0; it < 2; ++it) {
        int idx = it * 512 + tg;
        gofs[it] = (idx >> 4) * DH + (idx & 15) * 4;   // global f32 offset in tile
        kofs[it] = (idx >> 4) * QS + (idx & 15) * 4;   // LDS f16 offset in buffer
    }
    const int sofs = tg * 8;                          // wsV tile read offset (f16)
    const int wofs = (tg >> 3) * QS + (tg & 7) * 8;   // V LDS b128 write offset

    const f16* const ks_r = ksBase + l15 * QS + q4 * 8;   // QK^T A-frag: K row l15
    const f16* const vt_r = vtBase + l15 * QS + q4 * 16;  // PV A-frags: 16 f16

    // =============== PASS 1: s1[qc] = sum_k exp(2L) over group keys ===============
    float s1[2] = {0.f, 0.f};
    float4 kr[2];
    #pragma unroll
    for (int it = 0; it < 2; ++it)
        kr[it] = *(const float4*)&kbg[gofs[it]];
    #pragma unroll
    for (int it = 0; it < 2; ++it)
        *(uint2*)&ksBase[kofs[it]] =
            make_uint2(pk(kr[it].x, kr[it].y), pk(kr[it].z, kr[it].w));
    #pragma unroll
    for (int it = 0; it < 2; ++it)
        kr[it] = *(const float4*)&kbg[KT * DH + gofs[it]];
    __syncthreads();

    for (int kt = 0; kt < NKT_G; ++kt) {
        const int cur = (kt & 1) * KSB, nxt = KSB - cur;
        #pragma unroll
        for (int it = 0; it < 2; ++it)
            *(uint2*)&ksBase[nxt + kofs[it]] =
                make_uint2(pk(kr[it].x, kr[it].y), pk(kr[it].z, kr[it].w));
        {
            int tn = (kt + 2 < NKT_G) ? kt + 2 : NKT_G - 1;
            #pragma unroll
            for (int it = 0; it < 2; ++it)
                kr[it] = *(const float4*)&kbg[(size_t)tn * KT * DH + gofs[it]];
        }
        __builtin_amdgcn_s_setprio(1);
        #pragma unroll
        for (int kgi = 0; kgi < 4; ++kgi) {
            f16x8 b0 = *(const f16x8*)&ks_r[cur + kgi * 16 * QS];
            f16x8 b1 = *(const f16x8*)&ks_r[cur + kgi * 16 * QS + 32];
            #pragma unroll
            for (int qc = 0; qc < 2; ++qc) {
                f32x4 acc = {0.f, 0.f, 0.f, 0.f};
                acc = MFMA32(b0, aq[qc][0], acc);   // swapped: C[key][q], lane q = l15
                acc = MFMA32(b1, aq[qc][1], acc);
                s1[qc] += (EXP2(acc[0]) + EXP2(acc[1])) + (EXP2(acc[2]) + EXP2(acc[3]));
            }
        }
        __builtin_amdgcn_s_setprio(0);
        __syncthreads();
    }
    // reduce across q4 partitions; merge across key-groups via sred
    float inv1[2];
    #pragma unroll
    for (int qc = 0; qc < 2; ++qc) {
        float v = s1[qc];
        v += __shfl_xor(v, 16, 64);
        v += __shfl_xor(v, 32, 64);
        s1[qc] = v;
        if (lane < 16) sred[grp * 256 + wv7 * 32 + qc * 16 + lane] = v;
    }
    __syncthreads();
    #pragma unroll
    for (int qc = 0; qc < 2; ++qc) {
        s1[qc] += sred[(grp ^ 1) * 256 + wv7 * 32 + qc * 16 + l15];
        inv1[qc] = 0.5f / s1[qc];   // e2 = exp2((acc*e1) * 0.5/s1)  [acc = 2L*log2e]
    }

    // =============== PASS 2: e2, O^T += V^T P^T (2 q-subtiles) ===============
    f32x4 O[2][4];
    #pragma unroll
    for (int qc = 0; qc < 2; ++qc)
        #pragma unroll
        for (int dt = 0; dt < 4; ++dt) O[qc][dt] = (f32x4){0.f, 0.f, 0.f, 0.f};
    float l2[2] = {0.f, 0.f};

    f16x8 vrh;
    #pragma unroll
    for (int it = 0; it < 2; ++it)
        kr[it] = *(const float4*)&kbg[gofs[it]];                  // K(0) f32
    vrh = *(const f16x8*)&wsVh[(size_t)T0 * 4096 + sofs];         // V(0) f16
    #pragma unroll
    for (int it = 0; it < 2; ++it)
        *(uint2*)&ksBase[kofs[it]] =
            make_uint2(pk(kr[it].x, kr[it].y), pk(kr[it].z, kr[it].w));
    *(f16x8*)&vtBase[wofs] = vrh;
    #pragma unroll
    for (int it = 0; it < 2; ++it)
        kr[it] = *(const float4*)&kbg[KT * DH + gofs[it]];        // K(1)
    vrh = *(const f16x8*)&wsVh[(size_t)(T0 + 1) * 4096 + sofs];   // V(1)
    __syncthreads();

    for (int kt = 0; kt < NKT_G; ++kt) {
        const int cur = (kt & 1) * KSB, nxt = KSB - cur;
        #pragma unroll
        for (int it = 0; it < 2; ++it)
            *(uint2*)&ksBase[nxt + kofs[it]] =
                make_uint2(pk(kr[it].x, kr[it].y), pk(kr[it].z, kr[it].w));
        *(f16x8*)&vtBase[nxt + wofs] = vrh;
        { int tn = (kt + 2 < NKT_G) ? kt + 2 : NKT_G - 1;
          #pragma unroll
          for (int it = 0; it < 2; ++it)
              kr[it] = *(const float4*)&kbg[(size_t)tn * KT * DH + gofs[it]];
          vrh = *(const f16x8*)&wsVh[(size_t)(T0 + tn) * 4096 + sofs]; }
        // per kgi-PAIR: softmax(2p), softmax(2p+1) for both qc -> PV(pair p);
        // V A-frags (b128) shared across qc.
        __builtin_amdgcn_s_setprio(1);
        #pragma unroll
        for (int p = 0; p < 2; ++p) {
            f16x4 pfr[2][2];
            #pragma unroll
            for (int h = 0; h < 2; ++h) {
                const int kgi = p * 2 + h;
                f16x8 b0 = *(const f16x8*)&ks_r[cur + kgi * 16 * QS];
                f16x8 b1 = *(const f16x8*)&ks_r[cur + kgi * 16 * QS + 32];
                #pragma unroll
                for (int qc = 0; qc < 2; ++qc) {
                    f32x4 acc = {0.f, 0.f, 0.f, 0.f};
                    acc = MFMA32(b0, aq[qc][0], acc);
                    acc = MFMA32(b1, aq[qc][1], acc);
                    float e2r[4];
                    #pragma unroll
                    for (int r = 0; r < 4; ++r) {
                        float a  = acc[r];
                        float e1 = EXP2(a);
                        float e2 = EXP2((a * e1) * inv1[qc]);
                        l2[qc] += e2;
                        e2r[r] = e2;
                    }
                    union { f16x4 hh; unsigned u[2]; } P;
                    P.u[0] = pk(e2r[0], e2r[1]);
                    P.u[1] = pk(e2r[2], e2r[3]);
                    pfr[qc][h] = P.hh;
                }
            }
            #pragma unroll
            for (int dt = 0; dt < 4; ++dt) {
                f16x8 av = *(const f16x8*)&vt_r[cur + dt * 16 * QS + p * 8];
                f16x4 alo = __builtin_shufflevector(av, av, 0, 1, 2, 3);
                f16x4 ahi = __builtin_shufflevector(av, av, 4, 5, 6, 7);
                O[0][dt] = MFMA16(alo, pfr[0][0], O[0][dt]);
                O[0][dt] = MFMA16(ahi, pfr[0][1], O[0][dt]);
                O[1][dt] = MFMA16(alo, pfr[1][0], O[1][dt]);
                O[1][dt] = MFMA16(ahi, pfr[1][1], O[1][dt]);
            }
        }
        __builtin_amdgcn_s_setprio(0);
        __syncthreads();   // swap: protects Ks/Vt cur<->nxt
    }

    // ---- reduce l2 across q4 partitions; cross-group merge via dead LDS ----
    #pragma unroll
    for (int qc = 0; qc < 2; ++qc) {
        float v = l2[qc];
        v += __shfl_xor(v, 16, 64);
        v += __shfl_xor(v, 32, 64);
        l2[qc] = v;
    }
    const int rec = tg * 36;   // 36 f32 = 144 B/thread; 512 x 144 = 73728 B exact
    if (grp) {
        #pragma unroll
        for (int qc = 0; qc < 2; ++qc)
            #pragma unroll
            for (int dt = 0; dt < 4; ++dt)
                *(f32x4*)&obuf[rec + qc * 16 + dt * 4] = O[qc][dt];
        obuf[rec + 32] = l2[0];
        obuf[rec + 33] = l2[1];
    }
    __syncthreads();
    if (!grp) {
        #pragma unroll
        for (int qc = 0; qc < 2; ++qc) {
            #pragma unroll
            for (int dt = 0; dt < 4; ++dt)
                O[qc][dt] += *(const f32x4*)&obuf[rec + qc * 16 + dt * 4];
            const float invl2 = 1.0f / (l2[qc] + obuf[rec + 32 + qc]);
            const size_t orow = (size_t)(q0 + wv7 * 32 + qc * 16 + l15) * DH;
            #pragma unroll
            for (int dt = 0; dt < 4; ++dt) {
                float4 o;
                o.x = O[qc][dt][0] * invl2;
                o.y = O[qc][dt][1] * invl2;
                o.z = O[qc][dt][2] * invl2;
                o.w = O[qc][dt][3] * invl2;
                *(float4*)&ob[orow + dt * 16 + q4 * 4] = o;
            }
        }
    }
}

extern "C" void kernel_launch(void* const* d_in, const int* in_sizes, int n_in,
                              void* d_out, int out_size, void* d_ws, size_t ws_size,
                              hipStream_t stream) {
    const float* q = (const float*)d_in[0];
    const float* k = (const float*)d_in[1];
    const float* v = (const float*)d_in[2];
    const float* s = (const float*)d_in[3];
    float* out = (float*)d_out;
    f16* wsV = (f16*)d_ws;                       // 8 MB
    stk_prep<<<dim3(1024), dim3(256), 0, stream>>>(v, wsV);
    dim3 grid(32 * 8);    // bh = blockIdx&31 (XCD swizzle), q-tile = blockIdx>>5
    stk_attn_mfma<<<grid, 1024, SMEM_BYTES, stream>>>(q, k, wsV, s, out);
}

// Round 14
// 176.477 us; speedup vs baseline: 3.0862x; 1.2699x over previous
//
#include <hip/hip_runtime.h>

// STKBranch double-softmax attention, f16-MFMA 2-pass, R24:
//   = R18 VERBATIM with one token changed: __launch_bounds__(1024,8) ->
//   (1024,4). R18's key-split structure reached 83% occupancy but spilled
//   because (1024,8) caps VGPR at 64; its frame needs ~80. Cap 128 keeps
//   ~6 waves/SIMD (~24 waves/CU, vs R17's 16) with zero spill, single
//   kernel, no prep pass, no workspace.
//   Structure: 1024-thr blocks = 2 key-groups x 8 waves; group g owns keys
//   [g*1024,(g+1)*1024) for the same 128 q-rows; grid 512 -> 2 blocks/CU;
//   staging NOT duplicated; per-wave tile count halved (16) -> half the
//   barriers. s1 merged via LDS after pass 1; O/l2 partials merged through
//   the then-dead Ks/Vt LDS at the end.
//   Keeps R17's proven compute: swapped QK^T (C=KxQ^T) -> P in regs as the
//   16x16x16 PV B-frag; Vt permuted columns c(key)=((key>>2)&3)*16+
//   ((key>>4)&3)*4+(key&3) -> PV reads are b128; pair interleave softmax->PV;
//   prefetch-early; ones-MFMA l2; setprio; QS=72 bank-floor LDS.
// Math: L = scale*q@k^T ; w = softmax(2L) ; attn = softmax(L*w) ; out = attn@v
// |L| <= ~7 -> no max-subtraction. B=4 H=8 N=2048 D=64 fp32 io.

typedef _Float16 f16;
typedef f16 f16x8 __attribute__((ext_vector_type(8)));
typedef f16 f16x4 __attribute__((ext_vector_type(4)));
typedef float f32x4 __attribute__((ext_vector_type(4)));

#define MFMA32(a, b, c) __builtin_amdgcn_mfma_f32_16x16x32_f16((a), (b), (c), 0, 0, 0)
#define MFMA16(a, b, c) __builtin_amdgcn_mfma_f32_16x16x16f16((a), (b), (c), 0, 0, 0)
#define EXP2(x) __builtin_amdgcn_exp2f(x)   // v_exp_f32: D = 2^S0

#define N_CTX 2048
#define DH 64
#define KT 64
#define NKT_G 16          // tiles per key-group (1024 keys / KT)
#define ROWS 128          // 8 waves x 16 q-rows (per group)
#define QS 72             // universal LDS row stride (f16): 144 B
#define KSB (KT * QS)     // 4608 f16 = one Ks (or Vt) buffer
// smem carve (f16 units): KsG0 dbuf | KsG1 dbuf | VtG0 dbuf | VtG1 dbuf | sred
#define SMEM_F16 (4 * 2 * KSB + 512)      // 37376 f16 = 74752 B

#define C2 2.885390081777927f    // 2*log2(e), folded into Q fragments

__device__ inline unsigned pk(float a, float b) {
    typedef __fp16 fp16x2_t __attribute__((ext_vector_type(2)));
    union { fp16x2_t v; unsigned u; } x;
    x.v = __builtin_amdgcn_cvt_pkrtz(a, b);
    return x.u;
}

__global__ __launch_bounds__(1024, 4)
void stk_attn_mfma(const float* __restrict__ qg, const float* __restrict__ kg,
                   const float* __restrict__ vglob, const float* __restrict__ sg,
                   float* __restrict__ og) {
    extern __shared__ f16 smem[];

    const int tid  = threadIdx.x;
    const int wv   = tid >> 6;        // 0..15
    const int grp  = wv >> 3;         // key-group 0/1
    const int wv7  = wv & 7;          // wave within group
    const int lane = tid & 63;
    const int l15  = lane & 15;
    const int q4   = lane >> 4;
    const int tg   = (wv7 << 6) | lane;  // tid within group, 0..511
    const int vp   = tg & 31;         // V staging: key pair (2vp, 2vp+1)
    const int vgr  = tg >> 5;         // V staging: d-quad (0..15)
    const int bh   = blockIdx.x & 31; // XCD swizzle: head h -> blocks h+32j -> XCD h%8
    const int q0   = (blockIdx.x >> 5) * ROWS;
    const float scale2 = sg[0] * C2;  // fold 2*log2e: acc = 2L*log2e

    const float* qb = qg + (size_t)bh * N_CTX * DH;
    const float* kb = kg + (size_t)bh * N_CTX * DH;
    const float* vb = vglob + (size_t)bh * N_CTX * DH;
    float*       ob = og + (size_t)bh * N_CTX * DH;
    // group-local key base
    const float* kbg = kb + (size_t)grp * (NKT_G * KT) * DH;
    const float* vbg = vb + (size_t)grp * (NKT_G * KT) * DH;

    // ---- Q fragments direct from global (no LDS): row q0 + wv7*16 + l15 ----
    f16x8 aq[2];
    {
        const float* qrow = qb + (size_t)(q0 + wv7 * 16 + l15) * DH;
        #pragma unroll
        for (int kc = 0; kc < 2; ++kc) {
            float4 a0 = *(const float4*)&qrow[kc * 32 + q4 * 8];
            float4 a1 = *(const float4*)&qrow[kc * 32 + q4 * 8 + 4];
            union { f16x8 h; unsigned u[4]; } A;
            A.u[0] = pk(a0.x * scale2, a0.y * scale2);
            A.u[1] = pk(a0.z * scale2, a0.w * scale2);
            A.u[2] = pk(a1.x * scale2, a1.y * scale2);
            A.u[3] = pk(a1.z * scale2, a1.w * scale2);
            aq[kc] = A.h;
        }
    }

    // loop-invariant staging offsets: idx = it*512 + tg
    int kofs[2], gofs[2];
    #pragma unroll
    for (int it = 0; it < 2; ++it) {
        int idx = it * 512 + tg;
        gofs[it] = (idx >> 4) * DH + (idx & 15) * 4;   // global f32 offset within tile
        kofs[it] = (idx >> 4) * QS + (idx & 15) * 4;   // LDS f16 offset within buffer
    }
    // V staging permuted column base: keys (2vp, 2vp+1) -> columns (c2p, c2p+1)
    const int c2p = ((vp >> 1) & 3) * 16 + (vp >> 3) * 4 + (vp & 1) * 2;

    // group-private LDS bases (all ds offsets below are immediates)
    f16* const ksBase = smem + grp * (2 * KSB);
    f16* const vtBase = smem + 2 * (2 * KSB) + grp * (2 * KSB);
    float* const sred = (float*)(smem + 4 * (2 * KSB));   // 256 floats used
    float* const obuf = (float*)smem;                     // reduce scratch (epilogue)

    f16* const ks_w  = ksBase;
    const f16* const ks_r = ksBase + l15 * QS + q4 * 8;   // A-frag of QK^T: K row l15
    f16* const vt_w  = vtBase + (vgr * 4) * QS + c2p;
    const f16* const vt_r = vtBase + l15 * QS + q4 * 16;  // PV A-frags: 16 contiguous f16

    // =============== PASS 1: s1 = sum_k exp(2L) per q-row (group keys) ===============
    float s1 = 0.f;
    float4 kr[2];
    #pragma unroll
    for (int it = 0; it < 2; ++it)
        kr[it] = *(const float4*)&kbg[gofs[it]];
    #pragma unroll
    for (int it = 0; it < 2; ++it)
        *(uint2*)&ks_w[kofs[it]] =
            make_uint2(pk(kr[it].x, kr[it].y), pk(kr[it].z, kr[it].w));
    #pragma unroll
    for (int it = 0; it < 2; ++it)
        kr[it] = *(const float4*)&kbg[KT * DH + gofs[it]];
    __syncthreads();

    for (int kt = 0; kt < NKT_G; ++kt) {
        const int cur = (kt & 1) * KSB, nxt = KSB - cur;
        #pragma unroll
        for (int it = 0; it < 2; ++it)
            *(uint2*)&ks_w[nxt + kofs[it]] =
                make_uint2(pk(kr[it].x, kr[it].y), pk(kr[it].z, kr[it].w));
        {
            int tn = (kt + 2 < NKT_G) ? kt + 2 : NKT_G - 1;
            #pragma unroll
            for (int it = 0; it < 2; ++it)
                kr[it] = *(const float4*)&kbg[(size_t)tn * KT * DH + gofs[it]];
        }
        __builtin_amdgcn_s_setprio(1);
        #pragma unroll
        for (int kgi = 0; kgi < 4; ++kgi) {
            f16x8 b0 = *(const f16x8*)&ks_r[cur + kgi * 16 * QS];
            f16x8 b1 = *(const f16x8*)&ks_r[cur + kgi * 16 * QS + 32];
            f32x4 acc = {0.f, 0.f, 0.f, 0.f};
            acc = MFMA32(b0, aq[0], acc);   // swapped: C[key][q], lane q = l15
            acc = MFMA32(b1, aq[1], acc);
            s1 += (EXP2(acc[0]) + EXP2(acc[1])) + (EXP2(acc[2]) + EXP2(acc[3]));
        }
        __builtin_amdgcn_s_setprio(0);
        __syncthreads();
    }
    // reduce across q4 partitions, then across key-groups via sred
    s1 += __shfl_xor(s1, 16, 64);
    s1 += __shfl_xor(s1, 32, 64);
    if (lane < 16) sred[(grp << 7) + (wv7 << 4) + lane] = s1;
    __syncthreads();
    s1 += sred[((grp ^ 1) << 7) + (wv7 << 4) + l15];
    const float inv1 = 0.5f / s1;    // e2 = exp2((acc*e1) * 0.5/s1)  [acc = 2L*log2e]

    // =============== PASS 2: e2, O^T += V^T P^T, l2 via ones-MFMA ===============
    f32x4 O[4];
    #pragma unroll
    for (int dt = 0; dt < 4; ++dt) O[dt] = (f32x4){0.f, 0.f, 0.f, 0.f};
    f32x4 Oe = {0.f, 0.f, 0.f, 0.f};   // Oe[r] = sum_k P[k][q=l15] (group partial)
    const f16x4 ones = {(f16)1.f, (f16)1.f, (f16)1.f, (f16)1.f};

    float4 vr0, vr2;  // V prefetch: keys (2vp, 2vp+1), d-quad vgr*4..+3
    // prologue: Ks[0]<-K(g,0), Vt[0]<-V(g,0); kr<-K(g,1), vr<-V(g,1)
    #pragma unroll
    for (int it = 0; it < 2; ++it)
        kr[it] = *(const float4*)&kbg[gofs[it]];
    #pragma unroll
    for (int it = 0; it < 2; ++it)
        *(uint2*)&ks_w[kofs[it]] =
            make_uint2(pk(kr[it].x, kr[it].y), pk(kr[it].z, kr[it].w));
    {
        const float* vs = vbg + ((size_t)2 * vp) * DH + vgr * 4;
        float4 a0 = *(const float4*)(vs);
        float4 b0 = *(const float4*)(vs + DH);
        #pragma unroll
        for (int j = 0; j < 4; ++j)
            *(unsigned*)&vt_w[j * QS] = pk(((const float*)&a0)[j], ((const float*)&b0)[j]);
        const float* vs1 = vbg + ((size_t)(KT + 2 * vp)) * DH + vgr * 4;
        vr0 = *(const float4*)(vs1);
        vr2 = *(const float4*)(vs1 + DH);
    }
    #pragma unroll
    for (int it = 0; it < 2; ++it)
        kr[it] = *(const float4*)&kbg[KT * DH + gofs[it]];
    __syncthreads();

    for (int kt = 0; kt < NKT_G; ++kt) {
        const int cur = (kt & 1) * KSB, nxt = KSB - cur;
        // stage next K/V tile into the other buffers (overlaps all compute below)
        #pragma unroll
        for (int it = 0; it < 2; ++it)
            *(uint2*)&ks_w[nxt + kofs[it]] =
                make_uint2(pk(kr[it].x, kr[it].y), pk(kr[it].z, kr[it].w));
        #pragma unroll
        for (int j = 0; j < 4; ++j)
            *(unsigned*)&vt_w[nxt + j * QS] =
                pk(((const float*)&vr0)[j], ((const float*)&vr2)[j]);
        // prefetch K(kt+2), V(kt+2) issued BEFORE compute (full block in flight)
        {
            int tn = (kt + 2 < NKT_G) ? kt + 2 : NKT_G - 1;
            #pragma unroll
            for (int it = 0; it < 2; ++it)
                kr[it] = *(const float4*)&kbg[(size_t)tn * KT * DH + gofs[it]];
            const float* vs = vbg + ((size_t)(tn * KT + 2 * vp)) * DH + vgr * 4;
            vr0 = *(const float4*)(vs);
            vr2 = *(const float4*)(vs + DH);
        }
        // per kgi-PAIR: softmax(2p), softmax(2p+1) -> PV(pair p) via b128 V-frags
        __builtin_amdgcn_s_setprio(1);
        #pragma unroll
        for (int p = 0; p < 2; ++p) {
            f16x4 pfr[2];
            #pragma unroll
            for (int h = 0; h < 2; ++h) {
                const int kgi = p * 2 + h;
                f16x8 b0 = *(const f16x8*)&ks_r[cur + kgi * 16 * QS];
                f16x8 b1 = *(const f16x8*)&ks_r[cur + kgi * 16 * QS + 32];
                f32x4 acc = {0.f, 0.f, 0.f, 0.f};
                acc = MFMA32(b0, aq[0], acc);
                acc = MFMA32(b1, aq[1], acc);
                float e2r[4];
                #pragma unroll
                for (int r = 0; r < 4; ++r) {
                    float a  = acc[r];
                    float e1 = EXP2(a);
                    e2r[r] = EXP2((a * e1) * inv1);
                }
                union { f16x4 hh; unsigned u[2]; } P;
                P.u[0] = pk(e2r[0], e2r[1]);
                P.u[1] = pk(e2r[2], e2r[3]);
                pfr[h] = P.hh;
                Oe = MFMA16(ones, pfr[h], Oe);
            }
            // PV for kgi pair (2p, 2p+1): one b128 per dt covers both halves
            #pragma unroll
            for (int dt = 0; dt < 4; ++dt) {
                f16x8 av = *(const f16x8*)&vt_r[cur + dt * 16 * QS + p * 8];
                f16x4 alo = __builtin_shufflevector(av, av, 0, 1, 2, 3);
                f16x4 ahi = __builtin_shufflevector(av, av, 4, 5, 6, 7);
                O[dt] = MFMA16(alo, pfr[0], O[dt]);
                O[dt] = MFMA16(ahi, pfr[1], O[dt]);
            }
        }
        __builtin_amdgcn_s_setprio(0);
        __syncthreads();   // swap: protects Ks/Vt cur<->nxt for next iteration
    }

    // ---- cross-group merge of O/Oe via dead Ks/Vt LDS; group 0 writes ----
    const int rec = tg * 20;   // 20 f32/thread, 16B-aligned (80 B)
    if (grp) {
        #pragma unroll
        for (int dt = 0; dt < 4; ++dt)
            *(f32x4*)&obuf[rec + dt * 4] = O[dt];
        obuf[rec + 16] = Oe[0];
    }
    __syncthreads();
    if (!grp) {
        #pragma unroll
        for (int dt = 0; dt < 4; ++dt)
            O[dt] += *(const f32x4*)&obuf[rec + dt * 4];
        const float invl2 = 1.0f / (Oe[0] + obuf[rec + 16]);
        const size_t orow = (size_t)(q0 + wv7 * 16 + l15) * DH;
        #pragma unroll
        for (int dt = 0; dt < 4; ++dt) {
            float4 o;
            o.x = O[dt][0] * invl2;
            o.y = O[dt][1] * invl2;
            o.z = O[dt][2] * invl2;
            o.w = O[dt][3] * invl2;
            *(float4*)&ob[orow + dt * 16 + q4 * 4] = o;
        }
    }
}

extern "C" void kernel_launch(void* const* d_in, const int* in_sizes, int n_in,
                              void* d_out, int out_size, void* d_ws, size_t ws_size,
                              hipStream_t stream) {
    const float* q = (const float*)d_in[0];
    const float* k = (const float*)d_in[1];
    const float* v = (const float*)d_in[2];
    const float* s = (const float*)d_in[3];
    float* out = (float*)d_out;
    dim3 grid(32 * 16);   // bh = blockIdx&31 (XCD swizzle), q-tile = blockIdx>>5
    stk_attn_mfma<<<grid, 1024, SMEM_F16 * 2, stream>>>(q, k, v, s, out);
}